// Round 5
// baseline (498.305 us; speedup 1.0000x reference)
//
#include <hip/hip_runtime.h>
#include <hip/hip_bf16.h>
#include <stdint.h>

typedef __attribute__((ext_vector_type(8))) short short8;
typedef __attribute__((ext_vector_type(4))) float f32x4;
typedef unsigned int u32x4a __attribute__((vector_size(16)));             // 16B aligned
typedef unsigned int u32x4u __attribute__((vector_size(16), aligned(4))); // 4B aligned

__device__ inline unsigned short f2bf(float f) {
    union { float f; uint32_t u; } v; v.f = f;
    uint32_t u = v.u;
    uint32_t r = (u + 0x7FFFu + ((u >> 16) & 1u)) >> 16;
    return (unsigned short)r;
}

// async global->LDS, 16B per lane (per-lane global src; LDS dst = wave base + lane*16)
__device__ inline void gl_lds16(const unsigned short* g, unsigned short* l) {
    __builtin_amdgcn_global_load_lds(
        (const uint32_t __attribute__((address_space(1)))*)(const void*)g,
        (uint32_t __attribute__((address_space(3)))*)(void*)l, 16, 0, 0);
}

// ---------------- weight converts ----------------
__global__ void cvt_w1(const float* __restrict__ w, unsigned short* __restrict__ A1) {
    int idx = blockIdx.x * 256 + threadIdx.x;   // 65536 total
    int row = idx >> 8, k = idx & 255;
    float v = (k < 243) ? w[row * 243 + k] : 0.f;
    A1[idx] = f2bf(v);
}

// conv2 weights pre-shuffled into per-(m-tile, K-chunk) 16KB tiles, XOR-swizzled:
// A2t[tm][chunk][off16][j]  (off16 in [0,1024), j in [0,8))
//   row = off16>>3; sw = off16&7; koct = sw ^ (row&7); kk = chunk*64 + koct*8 + j
// reordered-k mapping: kk<18432: ic=kk/72, ky=(kk%72)>>3, kx=kk&7;  else kx=8 tail.
__global__ void cvt_w2(const float* __restrict__ w, unsigned short* __restrict__ A2t) {
    int idx = blockIdx.x * 256 + threadIdx.x;   // 5308416 total
    int j = idx & 7;
    int off16 = (idx >> 3) & 1023;
    int tile = idx >> 13;                 // 0..647
    int tm = tile / 324, chunk = tile - tm * 324;
    int row = off16 >> 3, sw = off16 & 7;
    int koct = sw ^ (row & 7);
    int kk = chunk * 64 + koct * 8 + j;
    int oc = tm * 128 + row;
    int ic, ky, kx;
    if (kk < 18432) { ic = kk / 72; int rem = kk - ic * 72; ky = rem >> 3; kx = rem & 7; }
    else { int j2 = kk - 18432; ic = j2 / 9; ky = j2 - ic * 9; kx = 8; }
    A2t[idx] = f2bf(w[((oc * 256 + ic) * 9 + ky) * 9 + kx]);
}

// ---------------- conv1 as implicit GEMM ----------------
__global__ __launch_bounds__(256) void conv1_gemm(
    const unsigned short* __restrict__ A,   // [256][256] bf16
    const float* __restrict__ x,            // [32][3][64][64]
    const float* __restrict__ bias,         // [256]
    unsigned short* __restrict__ h1)        // [32][256][56][56] bf16
{
    __shared__ __align__(16) unsigned short As[128 * 40];
    __shared__ __align__(16) unsigned short Bs[128 * 40];
    const int tid = threadIdx.x;
    const int m0 = blockIdx.y * 128;
    const int n0 = blockIdx.x * 128;
    const int lane = tid & 63;
    const int wave = tid >> 6;
    const int wy = wave & 1, wx = wave >> 1;
    const int l16 = lane & 15, q = lane >> 4;

    const int kp = tid & 15;
    const int gn = tid >> 4;
    int baseN[8];
#pragma unroll
    for (int j = 0; j < 8; ++j) {
        int n = n0 + gn * 8 + j;
        int b = n / 3136, p = n % 3136;
        int oy = p / 56, ox = p % 56;
        baseN[j] = b * 12288 + oy * 64 + ox;
    }

    f32x4 acc[4][4];
#pragma unroll
    for (int im = 0; im < 4; ++im)
#pragma unroll
        for (int in = 0; in < 4; ++in)
            acc[im][in] = (f32x4){0.f, 0.f, 0.f, 0.f};

    for (int k0 = 0; k0 < 256; k0 += 32) {
        __syncthreads();
#pragma unroll
        for (int s = 0; s < 2; ++s) {
            int slot = tid + s * 256;
            int row = slot >> 2, seg = slot & 3;
            u32x4a v = *(const u32x4a*)(A + (m0 + row) * 256 + k0 + seg * 8);
            *(u32x4a*)(&As[row * 40 + seg * 8]) = v;
        }
        int ka = k0 + 2 * kp, kb = ka + 1;
        int offa = 0, offb = 0;
        bool va = ka < 243, vb = kb < 243;
        if (va) { int c = ka / 81, t = ka % 81, ky = t / 9, kx = t % 9; offa = c * 4096 + ky * 64 + kx; }
        if (vb) { int c = kb / 81, t = kb % 81, ky = t / 9, kx = t % 9; offb = c * 4096 + ky * 64 + kx; }
#pragma unroll
        for (int j = 0; j < 8; ++j) {
            unsigned int ba = va ? (unsigned int)f2bf(x[baseN[j] + offa]) : 0u;
            unsigned int bb = vb ? (unsigned int)f2bf(x[baseN[j] + offb]) : 0u;
            *(unsigned int*)(&Bs[(gn * 8 + j) * 40 + 2 * kp]) = ba | (bb << 16);
        }
        __syncthreads();

        short8 af[4], bf[4];
#pragma unroll
        for (int im = 0; im < 4; ++im)
            af[im] = *(const short8*)(&As[(wy * 64 + im * 16 + l16) * 40 + q * 8]);
#pragma unroll
        for (int in = 0; in < 4; ++in)
            bf[in] = *(const short8*)(&Bs[(wx * 64 + in * 16 + l16) * 40 + q * 8]);
#pragma unroll
        for (int im = 0; im < 4; ++im)
#pragma unroll
            for (int in = 0; in < 4; ++in)
                acc[im][in] = __builtin_amdgcn_mfma_f32_16x16x32_bf16(af[im], bf[in], acc[im][in], 0, 0, 0);
    }

#pragma unroll
    for (int in = 0; in < 4; ++in) {
        int n = n0 + wx * 64 + in * 16 + l16;
        int b = n / 3136, p = n % 3136;
        int oy = p / 56, ox = p % 56;
#pragma unroll
        for (int im = 0; im < 4; ++im) {
#pragma unroll
            for (int r = 0; r < 4; ++r) {
                int oc = m0 + wy * 64 + im * 16 + q * 4 + r;
                float v = acc[im][in][r] + bias[oc];
                v = v > 0.f ? v : 0.f;
                h1[((b * 256 + oc) * 56 + oy) * 56 + ox] = f2bf(v);
            }
        }
    }
}

// ---------------- conv2: dual-DMA pipelined implicit GEMM, split-K x8, BK=64 ----------------
// A and B both staged via global_load_lds (double-buffered); one barrier per chunk.
// Bs layout: [koct 0..7][n 0..127][8 bf16]  (16B blocks, naturally bank-spread).
__global__ __launch_bounds__(256) void conv2_gemm(
    const unsigned short* __restrict__ A2t,  // [2][324][8192] bf16 swizzled tiles
    const unsigned short* __restrict__ h1,   // [32][256][56][56] bf16
    float* __restrict__ c2)                  // [32][256][576] fp32 (pre-zeroed)
{
    __shared__ __align__(16) unsigned short As[2][8192];   // 2 x 16KB
    __shared__ __align__(16) unsigned short Bs[2][8192];   // 2 x 16KB
    const int tid = threadIdx.x;
    const int n0 = blockIdx.x * 128;
    const int z = blockIdx.z;
    const int lane = tid & 63;
    const int wave = tid >> 6;
    const int wy = wave & 1, wx = wave >> 1;
    const int l16 = lane & 15, q = lane >> 4;

    // B DMA geometry: issue j' = wave*4 + i covers oct = j'>>1, n = (j'&1)*64 + lane.
    int bsrcA, bsrcB;   // h1 pixel base for n_local = lane and lane+64
    {
        int ngA = n0 + lane;
        int bA = ngA / 576, pA = ngA % 576;
        bsrcA = bA * 802816 + (2 * (pA / 24)) * 56 + 2 * (pA % 24);
        int ngB = n0 + 64 + lane;
        int bB = ngB / 576, pB = ngB % 576;
        bsrcB = bB * 802816 + (2 * (pB / 24)) * 56 + 2 * (pB % 24);
    }
    // tail staging geometry: thread covers n = tid&127, k-half = tid>>7
    const int tn = tid & 127, thalf = tid >> 7;
    int tbase;
    {
        int ng = n0 + tn;
        int b = ng / 576, p = ng % 576;
        tbase = b * 802816 + (2 * (p / 24)) * 56 + 2 * (p % 24) + 8;   // kx = 8
    }

    f32x4 acc[4][4];
#pragma unroll
    for (int im = 0; im < 4; ++im)
#pragma unroll
        for (int in = 0; in < 4; ++in)
            acc[im][in] = (f32x4){0.f, 0.f, 0.f, 0.f};

    const size_t tilebase = (size_t)blockIdx.y * 324 * 8192;
    uint32_t bR[16];

    auto issueA = [&](int c, int buf) {
        const unsigned short* at = A2t + tilebase + (size_t)c * 8192;
        int s0 = wave * 4;
#pragma unroll
        for (int i = 0; i < 4; ++i) {
            int sl = (s0 + i) * 64 + lane;
            gl_lds16(at + sl * 8, &As[buf][sl * 8]);
        }
    };
    auto issueB = [&](int c, int buf) {   // main chunks only (c < 288)
#pragma unroll
        for (int i = 0; i < 4; ++i) {
            int jp = wave * 4 + i;
            int octk = c * 8 + (jp >> 1);
            int ic = octk / 9, ky = octk - ic * 9;
            int src = ((jp & 1) ? bsrcB : bsrcA) + ic * 3136 + ky * 56;
            int sl = jp * 64 + lane;
            gl_lds16(h1 + src, &Bs[buf][sl * 8]);
        }
    };
    auto loadBtail = [&](int c) {
        int base = c * 64 + thalf * 32 - 18432;
#pragma unroll
        for (int p = 0; p < 16; ++p) {
            int j2 = base + 2 * p;
            int icA = j2 / 9, kyA = j2 - icA * 9;
            int icB = (j2 + 1) / 9, kyB = (j2 + 1) - icB * 9;
            uint32_t ba = h1[tbase + icA * 3136 + kyA * 56];
            uint32_t bb = h1[tbase + icB * 3136 + kyB * 56];
            bR[p] = ba | (bb << 16);
        }
    };
    auto writeBtail = [&](int buf) {
#pragma unroll
        for (int p = 0; p < 16; ++p) {
            int kk = thalf * 32 + 2 * p;
            int koct = kk >> 3, slot = kk & 7;
            *(uint32_t*)(&Bs[buf][(koct * 128 + tn) * 8 + slot]) = bR[p];
        }
    };

    const int nch = (324 - z + 7) >> 3;   // 41 for z<4, 40 for z>=4
    int c = z;
    issueA(c, 0);
    if (c < 288) issueB(c, 0); else loadBtail(c);
    for (int i = 0; i < nch; ++i) {
        const int cur = i & 1;
        const int cnext = c + 8;
        __syncthreads();                  // drains vmcnt: DMA for buf[cur] landed; prev compute done
        if (c >= 288) { writeBtail(cur); __syncthreads(); }
        if (i + 1 < nch) {
            issueA(cnext, cur ^ 1);       // flies across compute
            if (cnext < 288) issueB(cnext, cur ^ 1); else loadBtail(cnext);
        }
#pragma unroll
        for (int h = 0; h < 2; ++h) {
            short8 af[4], bf[4];
#pragma unroll
            for (int im = 0; im < 4; ++im) {
                int row = wy * 64 + im * 16 + l16;
                int koct = h * 4 + q;
                af[im] = *(const short8*)(&As[cur][(row * 8 + (koct ^ (row & 7))) * 8]);
            }
#pragma unroll
            for (int in = 0; in < 4; ++in)
                bf[in] = *(const short8*)(&Bs[cur][((h * 4 + q) * 128 + wx * 64 + in * 16 + l16) * 8]);
#pragma unroll
            for (int im = 0; im < 4; ++im)
#pragma unroll
                for (int in = 0; in < 4; ++in)
                    acc[im][in] = __builtin_amdgcn_mfma_f32_16x16x32_bf16(af[im], bf[in], acc[im][in], 0, 0, 0);
        }
        c = cnext;
    }

    // epilogue: accumulate split-K partial into c2
    const int m0 = blockIdx.y * 128;
#pragma unroll
    for (int in = 0; in < 4; ++in) {
        int nn = n0 + wx * 64 + in * 16 + l16;
        int bb = nn / 576, pp = nn % 576;
#pragma unroll
        for (int im = 0; im < 4; ++im) {
#pragma unroll
            for (int r = 0; r < 4; ++r) {
                int oc = m0 + wy * 64 + im * 16 + q * 4 + r;
                atomicAdd(&c2[(bb * 256 + oc) * 576 + pp], acc[im][in][r]);
            }
        }
    }
}

// ---------------- squash primary caps (+ conv2 bias) ----------------
__global__ void squash_caps(const float* __restrict__ c2, const float* __restrict__ bias,
                            float* __restrict__ caps) {
    int idx = blockIdx.x * 256 + threadIdx.x;   // 589824 = 32*32*576
    int b = idx / 18432;
    int rp = idx % 18432;
    int r = rp / 576, p = rp % 576;
    float s[8]; float n2 = 0.f;
#pragma unroll
    for (int d = 0; d < 8; ++d) {
        s[d] = c2[(b * 256 + r * 8 + d) * 576 + p] + bias[r * 8 + d];
        n2 += s[d] * s[d];
    }
    float sc = (n2 / (1.f + n2)) / sqrtf(n2 + 1e-8f);
#pragma unroll
    for (int d = 0; d < 8; ++d)
        caps[idx * 8 + d] = sc * s[d];
}

// ---------------- routing ----------------
// iteration 0: softmax is uniform (1/10) -> G = capsum/10
__global__ __launch_bounds__(64) void capsum0(const float* __restrict__ caps,
                                              float* __restrict__ G) {
    int r = blockIdx.x, b = blockIdx.y;
    const float* cp = caps + (size_t)(b * 32 + r) * 4608;
    int tid = threadIdx.x;
    f32x4 s0 = (f32x4){0.f, 0.f, 0.f, 0.f}, s1 = s0;
    for (int jv = 0; jv < 9; ++jv) {
        const f32x4* qp = (const f32x4*)(cp + (jv * 64 + tid) * 8);
        s0 += qp[0]; s1 += qp[1];
    }
#pragma unroll
    for (int off = 32; off > 0; off >>= 1) {
#pragma unroll
        for (int k = 0; k < 4; ++k) {
            s0[k] += __shfl_down(s0[k], off, 64);
            s1[k] += __shfl_down(s1[k], off, 64);
        }
    }
    if (tid == 0) {
        float g[8] = {s0[0], s0[1], s0[2], s0[3], s1[0], s1[1], s1[2], s1[3]};
        float* gp = G + (size_t)((b * 32 + r) * 10) * 8;
        for (int cc = 0; cc < 10; ++cc)
#pragma unroll
            for (int ii = 0; ii < 8; ++ii) gp[cc * 8 + ii] = g[ii] * 0.1f;
    }
}

// iterations 1,2: fused wv + accumulation
__global__ __launch_bounds__(64) void route_accum(const float* __restrict__ caps,
                                                  const float* __restrict__ W,
                                                  const float* __restrict__ V,
                                                  float* __restrict__ G) {
    int r = blockIdx.x, b = blockIdx.y;
    __shared__ float wv[80];
    __shared__ float red[80][64];
    int tid = threadIdx.x;
    for (int v = tid; v < 80; v += 64) {
        int cc = v >> 3, ii = v & 7;
        float s = 0.f;
#pragma unroll
        for (int o = 0; o < 16; ++o)
            s += W[((r * 10 + cc) * 8 + ii) * 16 + o] * V[(b * 10 + cc) * 16 + o];
        wv[v] = s;
    }
    __syncthreads();
    float g[80];
#pragma unroll
    for (int v = 0; v < 80; ++v) g[v] = 0.f;
    const float* cp = caps + (size_t)(b * 32 + r) * 4608;
    for (int j = 0; j < 9; ++j) {
        int p = j * 64 + tid;
        const f32x4* qp = (const f32x4*)(cp + p * 8);
        f32x4 c0 = qp[0], c1 = qp[1];
        float c8[8];
#pragma unroll
        for (int i = 0; i < 4; ++i) { c8[i] = c0[i]; c8[4 + i] = c1[i]; }
        float a[10]; float m = -1e30f;
#pragma unroll
        for (int cc = 0; cc < 10; ++cc) {
            float t = 0.f;
#pragma unroll
            for (int i = 0; i < 8; ++i) t += c8[i] * wv[cc * 8 + i];
            a[cc] = t; m = fmaxf(m, t);
        }
        float sum = 0.f;
#pragma unroll
        for (int cc = 0; cc < 10; ++cc) { a[cc] = __expf(a[cc] - m); sum += a[cc]; }
        float inv = 1.f / sum;
#pragma unroll
        for (int cc = 0; cc < 10; ++cc) {
            float w = a[cc] * inv;
#pragma unroll
            for (int i = 0; i < 8; ++i) g[cc * 8 + i] += w * c8[i];
        }
    }
#pragma unroll
    for (int v = 0; v < 80; ++v) red[v][tid] = g[v];
    __syncthreads();
    for (int v = tid; v < 80; v += 64) {
        float s = 0.f;
        for (int t = 0; t < 64; ++t) s += red[v][t];
        G[(b * 32 + r) * 80 + v] = s;
    }
}

__global__ __launch_bounds__(160) void sv_kernel(const float* __restrict__ G,
                                                 const float* __restrict__ W,
                                                 float* __restrict__ V,
                                                 float* __restrict__ out, int last) {
    int b = blockIdx.x;
    int c = threadIdx.x / 16, o = threadIdx.x % 16;
    __shared__ float sL[10][16];
    float s = 0.f;
    for (int r = 0; r < 32; ++r) {
        const float* g = G + ((b * 32 + r) * 10 + c) * 8;
        const float* w = W + ((r * 10 + c) * 8) * 16 + o;
#pragma unroll
        for (int i = 0; i < 8; ++i) s += g[i] * w[i * 16];
    }
    sL[c][o] = s;
    __syncthreads();
    float n2 = 0.f;
#pragma unroll
    for (int oo = 0; oo < 16; ++oo) { float t = sL[c][oo]; n2 += t * t; }
    float sc = (n2 / (1.f + n2)) / sqrtf(n2 + 1e-8f);
    float v = sc * s;
    V[(b * 10 + c) * 16 + o] += v;
    if (last) out[(b * 10 + c) * 16 + o] = v;
}

// ---------------- launch ----------------
extern "C" void kernel_launch(void* const* d_in, const int* in_sizes, int n_in,
                              void* d_out, int out_size, void* d_ws, size_t ws_size,
                              hipStream_t stream) {
    const float* x  = (const float*)d_in[0];
    const float* w1 = (const float*)d_in[1];
    const float* b1 = (const float*)d_in[2];
    const float* w2 = (const float*)d_in[3];
    const float* b2 = (const float*)d_in[4];
    const float* rw = (const float*)d_in[5];

    char* ws = (char*)d_ws;
    unsigned short* A1   = (unsigned short*)(ws);                  // 262,144 B
    unsigned short* A2   = (unsigned short*)(ws + 262144);         // 10,616,832 B
    unsigned short* h1   = (unsigned short*)(ws + 10878976);       // 51,380,224 B
    float*          c2   = (float*)(ws + 62259200);                // 18,874,368 B
    float*          caps = (float*)(ws + 81133568);                // 18,874,368 B
    float*          V    = (float*)(ws + 100007936);               // 20,480 B
    float*          G    = (float*)(ws + 100028416);               // 327,680 B

    hipLaunchKernelGGL(cvt_w1, dim3(256), dim3(256), 0, stream, w1, A1);
    hipLaunchKernelGGL(cvt_w2, dim3(20736), dim3(256), 0, stream, w2, A2);
    hipMemsetAsync(c2, 0, 18874368, stream);
    hipLaunchKernelGGL(conv1_gemm, dim3(784, 2), dim3(256), 0, stream, A1, x, b1, h1);
    hipLaunchKernelGGL(conv2_gemm, dim3(144, 2, 8), dim3(256), 0, stream, A2, h1, c2);
    hipLaunchKernelGGL(squash_caps, dim3(2304), dim3(256), 0, stream, c2, b2, caps);
    hipMemsetAsync(V, 0, 5120 * sizeof(float), stream);
    hipLaunchKernelGGL(capsum0, dim3(32, 32), dim3(64), 0, stream, caps, G);
    hipLaunchKernelGGL(sv_kernel, dim3(32), dim3(160), 0, stream, G, rw, V, (float*)d_out, 0);
    for (int it = 1; it < 3; ++it) {
        hipLaunchKernelGGL(route_accum, dim3(32, 32), dim3(64), 0, stream, caps, rw, V, G);
        hipLaunchKernelGGL(sv_kernel, dim3(32), dim3(160), 0, stream, G, rw, V,
                           (float*)d_out, it == 2 ? 1 : 0);
    }
}

// Round 6
// 470.933 us; speedup vs baseline: 1.0581x; 1.0581x over previous
//
#include <hip/hip_runtime.h>
#include <hip/hip_bf16.h>
#include <stdint.h>

typedef __attribute__((ext_vector_type(8))) short short8;
typedef __attribute__((ext_vector_type(4))) float f32x4;
typedef unsigned int u32x4a __attribute__((vector_size(16)));             // 16B aligned
typedef unsigned int u32x4u __attribute__((vector_size(16), aligned(4))); // 4B aligned

__device__ inline unsigned short f2bf(float f) {
    union { float f; uint32_t u; } v; v.f = f;
    uint32_t u = v.u;
    uint32_t r = (u + 0x7FFFu + ((u >> 16) & 1u)) >> 16;
    return (unsigned short)r;
}

// async global->LDS, 16B per lane (per-lane global src; LDS dst = wave base + lane*16)
__device__ inline void gl_lds16(const unsigned short* g, unsigned short* l) {
    __builtin_amdgcn_global_load_lds(
        (const uint32_t __attribute__((address_space(1)))*)(const void*)g,
        (uint32_t __attribute__((address_space(3)))*)(void*)l, 16, 0, 0);
}

// ---------------- weight converts ----------------
__global__ void cvt_w1(const float* __restrict__ w, unsigned short* __restrict__ A1) {
    int idx = blockIdx.x * 256 + threadIdx.x;   // 65536 total
    int row = idx >> 8, k = idx & 255;
    float v = (k < 243) ? w[row * 243 + k] : 0.f;
    A1[idx] = f2bf(v);
}

// conv2 weights pre-shuffled into per-(m-tile, K-chunk) 16KB tiles, XOR-swizzled:
// A2t[tm][chunk][off16][j]  (off16 = row*8 + sw; koct = sw ^ (row&7); kk = chunk*64+koct*8+j)
// reordered-k mapping: kk<18432: ic=kk/72, ky=(kk%72)>>3, kx=kk&7;  else kx=8 tail.
__global__ void cvt_w2(const float* __restrict__ w, unsigned short* __restrict__ A2t) {
    int idx = blockIdx.x * 256 + threadIdx.x;   // 5308416 total
    int j = idx & 7;
    int off16 = (idx >> 3) & 1023;
    int tile = idx >> 13;                 // 0..647
    int tm = tile / 324, chunk = tile - tm * 324;
    int row = off16 >> 3, sw = off16 & 7;
    int koct = sw ^ (row & 7);
    int kk = chunk * 64 + koct * 8 + j;
    int oc = tm * 128 + row;
    int ic, ky, kx;
    if (kk < 18432) { ic = kk / 72; int rem = kk - ic * 72; ky = rem >> 3; kx = rem & 7; }
    else { int j2 = kk - 18432; ic = j2 / 9; ky = j2 - ic * 9; kx = 8; }
    A2t[idx] = f2bf(w[((oc * 256 + ic) * 9 + ky) * 9 + kx]);
}

// ---------------- conv1 as implicit GEMM ----------------
__global__ __launch_bounds__(256) void conv1_gemm(
    const unsigned short* __restrict__ A,   // [256][256] bf16
    const float* __restrict__ x,            // [32][3][64][64]
    const float* __restrict__ bias,         // [256]
    unsigned short* __restrict__ h1)        // [32][256][56][56] bf16
{
    __shared__ __align__(16) unsigned short As[128 * 40];
    __shared__ __align__(16) unsigned short Bs[128 * 40];
    const int tid = threadIdx.x;
    const int m0 = blockIdx.y * 128;
    const int n0 = blockIdx.x * 128;
    const int lane = tid & 63;
    const int wave = tid >> 6;
    const int wy = wave & 1, wx = wave >> 1;
    const int l16 = lane & 15, q = lane >> 4;

    const int kp = tid & 15;
    const int gn = tid >> 4;
    int baseN[8];
#pragma unroll
    for (int j = 0; j < 8; ++j) {
        int n = n0 + gn * 8 + j;
        int b = n / 3136, p = n % 3136;
        int oy = p / 56, ox = p % 56;
        baseN[j] = b * 12288 + oy * 64 + ox;
    }

    f32x4 acc[4][4];
#pragma unroll
    for (int im = 0; im < 4; ++im)
#pragma unroll
        for (int in = 0; in < 4; ++in)
            acc[im][in] = (f32x4){0.f, 0.f, 0.f, 0.f};

    for (int k0 = 0; k0 < 256; k0 += 32) {
        __syncthreads();
#pragma unroll
        for (int s = 0; s < 2; ++s) {
            int slot = tid + s * 256;
            int row = slot >> 2, seg = slot & 3;
            u32x4a v = *(const u32x4a*)(A + (m0 + row) * 256 + k0 + seg * 8);
            *(u32x4a*)(&As[row * 40 + seg * 8]) = v;
        }
        int ka = k0 + 2 * kp, kb = ka + 1;
        int offa = 0, offb = 0;
        bool va = ka < 243, vb = kb < 243;
        if (va) { int c = ka / 81, t = ka % 81, ky = t / 9, kx = t % 9; offa = c * 4096 + ky * 64 + kx; }
        if (vb) { int c = kb / 81, t = kb % 81, ky = t / 9, kx = t % 9; offb = c * 4096 + ky * 64 + kx; }
#pragma unroll
        for (int j = 0; j < 8; ++j) {
            unsigned int ba = va ? (unsigned int)f2bf(x[baseN[j] + offa]) : 0u;
            unsigned int bb = vb ? (unsigned int)f2bf(x[baseN[j] + offb]) : 0u;
            *(unsigned int*)(&Bs[(gn * 8 + j) * 40 + 2 * kp]) = ba | (bb << 16);
        }
        __syncthreads();

        short8 af[4], bf[4];
#pragma unroll
        for (int im = 0; im < 4; ++im)
            af[im] = *(const short8*)(&As[(wy * 64 + im * 16 + l16) * 40 + q * 8]);
#pragma unroll
        for (int in = 0; in < 4; ++in)
            bf[in] = *(const short8*)(&Bs[(wx * 64 + in * 16 + l16) * 40 + q * 8]);
#pragma unroll
        for (int im = 0; im < 4; ++im)
#pragma unroll
            for (int in = 0; in < 4; ++in)
                acc[im][in] = __builtin_amdgcn_mfma_f32_16x16x32_bf16(af[im], bf[in], acc[im][in], 0, 0, 0);
    }

#pragma unroll
    for (int in = 0; in < 4; ++in) {
        int n = n0 + wx * 64 + in * 16 + l16;
        int b = n / 3136, p = n % 3136;
        int oy = p / 56, ox = p % 56;
#pragma unroll
        for (int im = 0; im < 4; ++im) {
#pragma unroll
            for (int r = 0; r < 4; ++r) {
                int oc = m0 + wy * 64 + im * 16 + q * 4 + r;
                float v = acc[im][in][r] + bias[oc];
                v = v > 0.f ? v : 0.f;
                h1[((b * 256 + oc) * 56 + oy) * 56 + ox] = f2bf(v);
            }
        }
    }
}

// ---------------- conv2: dual-DMA, half-chunk B buffers, 48KB LDS, split-K x8 ----------------
// As: 2 x 16KB chunk buffers (DMA, XOR-swizzled tiles).
// Bs: 2 x 8KB half-chunk buffers [oct 0..3][n 0..127][8] — B(h) of any chunk -> Bs[h].
__global__ __launch_bounds__(256, 3) void conv2_gemm(
    const unsigned short* __restrict__ A2t,  // [2][324][8192] bf16 swizzled tiles
    const unsigned short* __restrict__ h1,   // [32][256][56][56] bf16
    float* __restrict__ c2)                  // [32][256][576] fp32 (pre-zeroed)
{
    __shared__ __align__(16) unsigned short As[2][8192];   // 32KB
    __shared__ __align__(16) unsigned short Bs[2][4096];   // 16KB
    const int tid = threadIdx.x;
    const int n0 = blockIdx.x * 128;
    const int z = blockIdx.z;
    const int lane = tid & 63;
    const int wave = tid >> 6;
    const int wy = wave & 1, wx = wave >> 1;
    const int l16 = lane & 15, q = lane >> 4;

    // B DMA lane geometry: n_local = lane (+64)
    int bsrcA, bsrcB;
    {
        int ngA = n0 + lane;
        int bA = ngA / 576, pA = ngA % 576;
        bsrcA = bA * 802816 + (2 * (pA / 24)) * 56 + 2 * (pA % 24);
        int ngB = n0 + 64 + lane;
        int bB = ngB / 576, pB = ngB % 576;
        bsrcB = bB * 802816 + (2 * (pB / 24)) * 56 + 2 * (pB % 24);
    }
    // tail geometry
    const int tn = tid & 127, thalf = tid >> 7;
    int tbase;
    {
        int ng = n0 + tn;
        int b = ng / 576, p = ng % 576;
        tbase = b * 802816 + (2 * (p / 24)) * 56 + 2 * (p % 24) + 8;   // kx = 8
    }

    f32x4 acc[4][4];
#pragma unroll
    for (int im = 0; im < 4; ++im)
#pragma unroll
        for (int in = 0; in < 4; ++in)
            acc[im][in] = (f32x4){0.f, 0.f, 0.f, 0.f};

    const size_t tilebase = (size_t)blockIdx.y * 324 * 8192;
    uint32_t bR[16];

    auto issueAh = [&](int c, int buf, int half) {   // 8KB half: rows 64*half..64*half+63
        const unsigned short* at = A2t + tilebase + (size_t)c * 8192;
#pragma unroll
        for (int i = 0; i < 2; ++i) {
            int sl = (half * 8 + wave * 2 + i) * 64 + lane;
            gl_lds16(at + sl * 8, &As[buf][sl * 8]);
        }
    };
    auto issueB = [&](int c, int h) {                // 8KB half-chunk -> Bs[h]
#pragma unroll
        for (int i = 0; i < 2; ++i) {
            int j = wave * 2 + i;                    // 0..7
            int octl = j >> 1;
            int octk = c * 8 + h * 4 + octl;
            int ic = octk / 9, ky = octk - ic * 9;
            int src = ((j & 1) ? bsrcB : bsrcA) + ic * 3136 + ky * 56;
            gl_lds16(h1 + src, &Bs[h][(octl * 128 + (j & 1) * 64 + lane) * 8]);
        }
    };
    auto loadBtail = [&](int c) {
        int base = c * 64 + thalf * 32 - 18432;
#pragma unroll
        for (int p = 0; p < 16; ++p) {
            int j2 = base + 2 * p;
            int icA = j2 / 9, kyA = j2 - icA * 9;
            int icB = (j2 + 1) / 9, kyB = (j2 + 1) - icB * 9;
            uint32_t ba = h1[tbase + icA * 3136 + kyA * 56];
            uint32_t bb = h1[tbase + icB * 3136 + kyB * 56];
            bR[p] = ba | (bb << 16);
        }
    };
    auto writeBtail = [&]() {
#pragma unroll
        for (int p = 0; p < 16; ++p) {
            int kk = thalf * 32 + 2 * p;
            int koct = kk >> 3;
            *(uint32_t*)(&Bs[koct >> 2][((koct & 3) * 128 + tn) * 8 + (kk & 7)]) = bR[p];
        }
    };
    auto compute = [&](int h, int cur) {
        short8 af[4], bf[4];
        int koct = h * 4 + q;
#pragma unroll
        for (int im = 0; im < 4; ++im) {
            int row = wy * 64 + im * 16 + l16;
            af[im] = *(const short8*)(&As[cur][(row * 8 + (koct ^ (row & 7))) * 8]);
        }
#pragma unroll
        for (int in = 0; in < 4; ++in)
            bf[in] = *(const short8*)(&Bs[h][(q * 128 + wx * 64 + in * 16 + l16) * 8]);
#pragma unroll
        for (int im = 0; im < 4; ++im)
#pragma unroll
            for (int in = 0; in < 4; ++in)
                acc[im][in] = __builtin_amdgcn_mfma_f32_16x16x32_bf16(af[im], bf[in], acc[im][in], 0, 0, 0);
    };

    const int nch = (324 - z + 7) >> 3;   // 41 for z<4, 40 for z>=4; tail starts at i=36
    int c = z;
    issueAh(c, 0, 0); issueAh(c, 0, 1);
    issueB(c, 0);
    for (int i = 0; i < 36; ++i) {
        const int cur = i & 1, nxt = cur ^ 1;
        const int cn = c + 8;
        __syncthreads();                    // A(c) full + B(c,h0) landed; prev h1 compute done
        issueB(c, 1);                       // -> Bs[1], flies during h0 compute
        issueAh(cn, nxt, 0);
        compute(0, cur);
        __syncthreads();                    // B(c,h1) + A(cn)h0 landed; h0 compute done
        if (i + 1 < 36) issueB(cn, 0);      // -> Bs[0], flies during h1 compute
        else loadBtail(cn);                 // first tail chunk prefetch to regs
        issueAh(cn, nxt, 1);
        compute(1, cur);
        c = cn;
    }
    for (int i = 36; i < nch; ++i) {        // tail chunks (kx=8), register path
        const int cur = i & 1, nxt = cur ^ 1;
        const int cn = c + 8;
        __syncthreads();                    // A(c) landed; prev compute done
        writeBtail();
        __syncthreads();                    // Bs ready
        if (i + 1 < nch) {
            issueAh(cn, nxt, 0); issueAh(cn, nxt, 1);
            loadBtail(cn);                  // flies during compute
        }
        compute(0, cur);
        compute(1, cur);
        c = cn;
    }

    // epilogue: accumulate split-K partial into c2
    const int m0 = blockIdx.y * 128;
#pragma unroll
    for (int in = 0; in < 4; ++in) {
        int nn = n0 + wx * 64 + in * 16 + l16;
        int bb = nn / 576, pp = nn % 576;
#pragma unroll
        for (int im = 0; im < 4; ++im) {
#pragma unroll
            for (int r = 0; r < 4; ++r) {
                int oc = m0 + wy * 64 + im * 16 + q * 4 + r;
                atomicAdd(&c2[(bb * 256 + oc) * 576 + pp], acc[im][in][r]);
            }
        }
    }
}

// ---------------- squash primary caps (+ conv2 bias) ----------------
__global__ void squash_caps(const float* __restrict__ c2, const float* __restrict__ bias,
                            float* __restrict__ caps) {
    int idx = blockIdx.x * 256 + threadIdx.x;   // 589824 = 32*32*576
    int b = idx / 18432;
    int rp = idx % 18432;
    int r = rp / 576, p = rp % 576;
    float s[8]; float n2 = 0.f;
#pragma unroll
    for (int d = 0; d < 8; ++d) {
        s[d] = c2[(b * 256 + r * 8 + d) * 576 + p] + bias[r * 8 + d];
        n2 += s[d] * s[d];
    }
    float sc = (n2 / (1.f + n2)) / sqrtf(n2 + 1e-8f);
#pragma unroll
    for (int d = 0; d < 8; ++d)
        caps[idx * 8 + d] = sc * s[d];
}

// ---------------- routing ----------------
// iteration 0: softmax is uniform (1/10) -> G = capsum/10
__global__ __launch_bounds__(64) void capsum0(const float* __restrict__ caps,
                                              float* __restrict__ G) {
    int r = blockIdx.x, b = blockIdx.y;
    const float* cp = caps + (size_t)(b * 32 + r) * 4608;
    int tid = threadIdx.x;
    f32x4 s0 = (f32x4){0.f, 0.f, 0.f, 0.f}, s1 = s0;
    for (int jv = 0; jv < 9; ++jv) {
        const f32x4* qp = (const f32x4*)(cp + (jv * 64 + tid) * 8);
        s0 += qp[0]; s1 += qp[1];
    }
#pragma unroll
    for (int off = 32; off > 0; off >>= 1) {
#pragma unroll
        for (int k = 0; k < 4; ++k) {
            s0[k] += __shfl_down(s0[k], off, 64);
            s1[k] += __shfl_down(s1[k], off, 64);
        }
    }
    if (tid == 0) {
        float g[8] = {s0[0], s0[1], s0[2], s0[3], s1[0], s1[1], s1[2], s1[3]};
        float* gp = G + (size_t)((b * 32 + r) * 10) * 8;
        for (int cc = 0; cc < 10; ++cc)
#pragma unroll
            for (int ii = 0; ii < 8; ++ii) gp[cc * 8 + ii] = g[ii] * 0.1f;
    }
}

// iterations 1,2: fused wv + accumulation
__global__ __launch_bounds__(64) void route_accum(const float* __restrict__ caps,
                                                  const float* __restrict__ W,
                                                  const float* __restrict__ V,
                                                  float* __restrict__ G) {
    int r = blockIdx.x, b = blockIdx.y;
    __shared__ float wv[80];
    __shared__ float red[80][64];
    int tid = threadIdx.x;
    for (int v = tid; v < 80; v += 64) {
        int cc = v >> 3, ii = v & 7;
        float s = 0.f;
#pragma unroll
        for (int o = 0; o < 16; ++o)
            s += W[((r * 10 + cc) * 8 + ii) * 16 + o] * V[(b * 10 + cc) * 16 + o];
        wv[v] = s;
    }
    __syncthreads();
    float g[80];
#pragma unroll
    for (int v = 0; v < 80; ++v) g[v] = 0.f;
    const float* cp = caps + (size_t)(b * 32 + r) * 4608;
    for (int j = 0; j < 9; ++j) {
        int p = j * 64 + tid;
        const f32x4* qp = (const f32x4*)(cp + p * 8);
        f32x4 c0 = qp[0], c1 = qp[1];
        float c8[8];
#pragma unroll
        for (int i = 0; i < 4; ++i) { c8[i] = c0[i]; c8[4 + i] = c1[i]; }
        float a[10]; float m = -1e30f;
#pragma unroll
        for (int cc = 0; cc < 10; ++cc) {
            float t = 0.f;
#pragma unroll
            for (int i = 0; i < 8; ++i) t += c8[i] * wv[cc * 8 + i];
            a[cc] = t; m = fmaxf(m, t);
        }
        float sum = 0.f;
#pragma unroll
        for (int cc = 0; cc < 10; ++cc) { a[cc] = __expf(a[cc] - m); sum += a[cc]; }
        float inv = 1.f / sum;
#pragma unroll
        for (int cc = 0; cc < 10; ++cc) {
            float w = a[cc] * inv;
#pragma unroll
            for (int i = 0; i < 8; ++i) g[cc * 8 + i] += w * c8[i];
        }
    }
#pragma unroll
    for (int v = 0; v < 80; ++v) red[v][tid] = g[v];
    __syncthreads();
    for (int v = tid; v < 80; v += 64) {
        float s = 0.f;
        for (int t = 0; t < 64; ++t) s += red[v][t];
        G[(b * 32 + r) * 80 + v] = s;
    }
}

__global__ __launch_bounds__(160) void sv_kernel(const float* __restrict__ G,
                                                 const float* __restrict__ W,
                                                 float* __restrict__ V,
                                                 float* __restrict__ out, int last) {
    int b = blockIdx.x;
    int c = threadIdx.x / 16, o = threadIdx.x % 16;
    __shared__ float sL[10][16];
    float s = 0.f;
    for (int r = 0; r < 32; ++r) {
        const float* g = G + ((b * 32 + r) * 10 + c) * 8;
        const float* w = W + ((r * 10 + c) * 8) * 16 + o;
#pragma unroll
        for (int i = 0; i < 8; ++i) s += g[i] * w[i * 16];
    }
    sL[c][o] = s;
    __syncthreads();
    float n2 = 0.f;
#pragma unroll
    for (int oo = 0; oo < 16; ++oo) { float t = sL[c][oo]; n2 += t * t; }
    float sc = (n2 / (1.f + n2)) / sqrtf(n2 + 1e-8f);
    float v = sc * s;
    V[(b * 10 + c) * 16 + o] += v;
    if (last) out[(b * 10 + c) * 16 + o] = v;
}

// ---------------- launch ----------------
extern "C" void kernel_launch(void* const* d_in, const int* in_sizes, int n_in,
                              void* d_out, int out_size, void* d_ws, size_t ws_size,
                              hipStream_t stream) {
    const float* x  = (const float*)d_in[0];
    const float* w1 = (const float*)d_in[1];
    const float* b1 = (const float*)d_in[2];
    const float* w2 = (const float*)d_in[3];
    const float* b2 = (const float*)d_in[4];
    const float* rw = (const float*)d_in[5];

    char* ws = (char*)d_ws;
    unsigned short* A1   = (unsigned short*)(ws);                  // 262,144 B
    unsigned short* A2   = (unsigned short*)(ws + 262144);         // 10,616,832 B
    unsigned short* h1   = (unsigned short*)(ws + 10878976);       // 51,380,224 B
    float*          c2   = (float*)(ws + 62259200);                // 18,874,368 B
    float*          caps = (float*)(ws + 81133568);                // 18,874,368 B
    float*          V    = (float*)(ws + 100007936);               // 20,480 B
    float*          G    = (float*)(ws + 100028416);               // 327,680 B

    hipLaunchKernelGGL(cvt_w1, dim3(256), dim3(256), 0, stream, w1, A1);
    hipLaunchKernelGGL(cvt_w2, dim3(20736), dim3(256), 0, stream, w2, A2);
    hipMemsetAsync(c2, 0, 18874368, stream);
    hipLaunchKernelGGL(conv1_gemm, dim3(784, 2), dim3(256), 0, stream, A1, x, b1, h1);
    hipLaunchKernelGGL(conv2_gemm, dim3(144, 2, 8), dim3(256), 0, stream, A2, h1, c2);
    hipLaunchKernelGGL(squash_caps, dim3(2304), dim3(256), 0, stream, c2, b2, caps);
    hipMemsetAsync(V, 0, 5120 * sizeof(float), stream);
    hipLaunchKernelGGL(capsum0, dim3(32, 32), dim3(64), 0, stream, caps, G);
    hipLaunchKernelGGL(sv_kernel, dim3(32), dim3(160), 0, stream, G, rw, V, (float*)d_out, 0);
    for (int it = 1; it < 3; ++it) {
        hipLaunchKernelGGL(route_accum, dim3(32, 32), dim3(64), 0, stream, caps, rw, V, G);
        hipLaunchKernelGGL(sv_kernel, dim3(32), dim3(160), 0, stream, G, rw, V,
                           (float*)d_out, it == 2 ? 1 : 0);
    }
}